// Round 10
// baseline (368.308 us; speedup 1.0000x reference)
//
#include <hip/hip_runtime.h>
#include <hip/hip_bf16.h>

#define DIM 512
#define BATCH 512
#define CCLS 100000
#define BM 256
#define BN 128
#define NT 782   // ceil(100000/128)

typedef __attribute__((ext_vector_type(4))) float f32x4;

__device__ __forceinline__ void async_copy16(const unsigned char* g, unsigned char* l) {
  __builtin_amdgcn_global_load_lds((const __attribute__((address_space(1))) void*)g,
                                   (__attribute__((address_space(3))) void*)l, 16, 0, 0);
}

// One wave per row: read fp32 row, L2-normalize (fp32), write fp8 e4m3 row.
// (R0's kernel, proven at HBM roofline ~41 us.)
__global__ __launch_bounds__(256) void rownorm_fp8(const float* __restrict__ wt,
                                                   const float* __restrict__ x,
                                                   unsigned char* __restrict__ wn,
                                                   unsigned char* __restrict__ xn) {
  int wave = threadIdx.x >> 6;
  int lane = threadIdx.x & 63;
  int row4 = blockIdx.x * 4 + wave;
  const float* in;
  unsigned char* out;
  int row;
  if (row4 < CCLS) { in = wt; out = wn; row = row4; }
  else             { in = x;  out = xn; row = row4 - CCLS; }
  const float4* src = (const float4*)(in + (size_t)row * DIM);
  float4 v0 = src[2 * lane];
  float4 v1 = src[2 * lane + 1];
  float ss = v0.x*v0.x + v0.y*v0.y + v0.z*v0.z + v0.w*v0.w
           + v1.x*v1.x + v1.y*v1.y + v1.z*v1.z + v1.w*v1.w;
  #pragma unroll
  for (int off = 32; off > 0; off >>= 1) ss += __shfl_xor(ss, off, 64);
  float r = 1.0f / fmaxf(sqrtf(ss), 1e-12f);
  int p0 = __builtin_amdgcn_cvt_pk_fp8_f32(v0.x * r, v0.y * r, 0, false);
  p0     = __builtin_amdgcn_cvt_pk_fp8_f32(v0.z * r, v0.w * r, p0, true);
  int p1 = __builtin_amdgcn_cvt_pk_fp8_f32(v1.x * r, v1.y * r, 0, false);
  p1     = __builtin_amdgcn_cvt_pk_fp8_f32(v1.z * r, v1.w * r, p1, true);
  ((int2*)(out + (size_t)row * DIM))[lane] = make_int2(p0, p1);
}

// 256x128 tile fp8 GEMM, K=512, BK=64 (8 iters), 512 threads = 8 waves
// (4m x 2n), 64x64 per-wave tile = R0's exact no-spill register profile
// (acc[4][4] = 64 AGPR, VGPR_Count 64 at (512,4)).
// NEW vs R0: double-buffered LDS (A 2x16K + B 2x8K = 48K -> 3 blocks/CU,
// 6 waves/SIMD) with 2-phase prefetch: stage(kk+1) BEFORE compute(kk),
// ONE vmcnt(0)+s_barrier per iter (R3's proven-correct idiom). Staging
// sources (wn/xn) are L3-resident (written by rownorm) -> loads are
// L2/L3-hit and fully covered by the 6-wave MFMA rotation.
// LDS rows are 64 fp8 bytes (one BK slice), 16B-chunk XOR(m&3) swizzle.
__global__ __launch_bounds__(512, 4) void cosface_gemm(
    const unsigned char* __restrict__ xn,
    const unsigned char* __restrict__ wn,
    const int* __restrict__ gt,
    float* __restrict__ partial,
    float* __restrict__ tgt) {
  __shared__ __align__(16) unsigned char lds_a[2][BM * 64];   // 32 KB
  __shared__ __align__(16) unsigned char lds_b[2][BN * 64];   // 16 KB
  __shared__ float lds_rowsum[BM];
  __shared__ int lds_gt[BM];

  const int tid = threadIdx.x;
  const int lane = tid & 63;
  const int w = tid >> 6;          // wave 0..7
  const int wm = w >> 1;           // 0..3  (64-row slice)
  const int wn_ = w & 1;           // 0..1  (64-col slice)

  // Bijective XCD swizzle (m204 form): 1564 = 4 xcds x 196 + 4 x 195.
  // mt-pair of one nt is wgid-consecutive -> same XCD L2 shares wn rows.
  int orig = blockIdx.x;
  int xcd = orig & 7;
  int f = (xcd < 4 ? xcd * 196 : 4 * 196 + (xcd - 4) * 195) + (orig >> 3);
  const int mt = f & 1;            // 0..1
  const int nt = f >> 1;           // 0..781

  if (tid < BM) {
    lds_rowsum[tid] = 0.f;
    lds_gt[tid] = gt[mt * BM + tid];
  }

  // Staging (BK=64): A 1024 chunks of 16B (2/thread), B 512 (1/thread).
  // chunk c -> row m = c>>2, slot qs = c&3, content chunk qg = qs ^ (m&3).
  unsigned int oa[2];
  unsigned int ob;
  #pragma unroll
  for (int j = 0; j < 2; ++j) {
    int c = j * 512 + tid;
    int m = c >> 2;
    int qg = (c & 3) ^ (m & 3);
    oa[j] = (unsigned int)(mt * BM + m) * DIM + qg * 16;
  }
  {
    int m = tid >> 2;
    int qg = (tid & 3) ^ (m & 3);
    int rowB = nt * BN + m;
    if (rowB >= CCLS) rowB = CCLS - 1;   // clamp; excluded in epilogue
    ob = (unsigned int)rowB * DIM + qg * 16;
  }

#define STAGE(sel, kk) do {                                                  \
    _Pragma("unroll")                                                        \
    for (int j = 0; j < 2; ++j)                                              \
      async_copy16(xn + oa[j] + (kk) * 64,                                   \
                   &lds_a[sel][(j * 512 + tid) * 16]);                       \
    async_copy16(wn + ob + (kk) * 64, &lds_b[sel][tid * 16]);                \
  } while (0)

  f32x4 acc[4][4];
  #pragma unroll
  for (int i = 0; i < 4; ++i)
    #pragma unroll
    for (int j = 0; j < 4; ++j)
      acc[i][j] = (f32x4){0.f, 0.f, 0.f, 0.f};

  const int quad = lane >> 4;
  const int l15 = lane & 15;
  const int sw = l15 & 3;          // (row & 3); row offsets are x16 -> const
  // Fragment chunk for k-slice s: cs = s*2 + (quad>>1), h = (quad&1)*8.
  const int csbase = quad >> 1;
  const int h = (quad & 1) * 8;

  // Prologue: stage tile 0; full drain (also covers rowsum/gt init).
  STAGE(0, 0);
  __syncthreads();

  #pragma unroll
  for (int kk = 0; kk < 8; ++kk) {
    const int cur = kk & 1;
    if (kk < 7) STAGE(cur ^ 1, kk + 1);   // prefetch next tile

    #pragma unroll
    for (int s = 0; s < 2; ++s) {
      int cs = s * 2 + csbase;
      long long af[4], bf[4];
      #pragma unroll
      for (int i = 0; i < 4; ++i)
        af[i] = *(const long long*)&lds_a[cur][(wm * 64 + i * 16 + l15) * 64 + ((cs ^ sw) * 16) + h];
      #pragma unroll
      for (int j = 0; j < 4; ++j)
        bf[j] = *(const long long*)&lds_b[cur][(wn_ * 64 + j * 16 + l15) * 64 + ((cs ^ sw) * 16) + h];
      #pragma unroll
      for (int i = 0; i < 4; ++i)
        #pragma unroll
        for (int j = 0; j < 4; ++j)
          acc[i][j] = __builtin_amdgcn_mfma_f32_16x16x32_fp8_fp8(af[i], bf[j], acc[i][j], 0, 0, 0);
    }

    if (kk < 7) {
      // Publish this wave's prefetch, then barrier (reads of buf cur are
      // complete via lgkm before the barrier; next iter overwrites cur).
      asm volatile("s_waitcnt vmcnt(0)" ::: "memory");
      __builtin_amdgcn_s_barrier();
      asm volatile("" ::: "memory");
    }
  }
#undef STAGE

  // Epilogue (R0's, verified): logit = 64*cos (-22.4 at gt);
  // rowsum += sum_n exp(logit-64).
  #pragma unroll
  for (int i = 0; i < 4; ++i) {
    #pragma unroll
    for (int reg = 0; reg < 4; ++reg) {
      int m_loc = wm * 64 + i * 16 + quad * 4 + reg;
      int m_g = mt * BM + m_loc;
      int gtm = lds_gt[m_loc];
      float s = 0.f;
      #pragma unroll
      for (int j = 0; j < 4; ++j) {
        int n_g = nt * BN + wn_ * 64 + j * 16 + l15;
        float logit = 64.f * acc[i][j][reg];
        if (n_g == gtm) {
          logit -= 64.f * 0.35f;
          tgt[m_g] = logit;
        }
        if (n_g < CCLS) s += __expf(logit - 64.f);
      }
      #pragma unroll
      for (int off = 1; off < 16; off <<= 1) s += __shfl_xor(s, off, 64);
      if (l15 == 0) atomicAdd(&lds_rowsum[m_loc], s);
    }
  }
  __syncthreads();
  if (tid < BM)
    partial[(size_t)(mt * BM + tid) * NT + nt] = lds_rowsum[tid];
}

// One wave per row m: sum partial[m][0..NT) (contiguous), emit nll[m].
__global__ __launch_bounds__(64) void nll_rows(const float* __restrict__ partial,
                                               const float* __restrict__ tgt,
                                               float* __restrict__ nll) {
  int m = blockIdx.x;
  int lane = threadIdx.x;
  const float* row = partial + (size_t)m * NT;
  float s = 0.f;
  for (int t = lane; t < NT; t += 64) s += row[t];
  #pragma unroll
  for (int off = 32; off > 0; off >>= 1) s += __shfl_xor(s, off, 64);
  if (lane == 0) nll[m] = (logf(s) + 64.f) - tgt[m];
}

__global__ __launch_bounds__(512) void reduce_mean(const float* __restrict__ nll,
                                                   float* __restrict__ out) {
  __shared__ float red[BATCH];
  int m = threadIdx.x;
  red[m] = nll[m];
  __syncthreads();
  for (int k = 256; k > 0; k >>= 1) {
    if (m < k) red[m] += red[m + k];
    __syncthreads();
  }
  if (m == 0) out[0] = red[0] * (1.0f / BATCH);
}

extern "C" void kernel_launch(void* const* d_in, const int* in_sizes, int n_in,
                              void* d_out, int out_size, void* d_ws, size_t ws_size,
                              hipStream_t stream) {
  const float* x  = (const float*)d_in[0];
  const int*   gt = (const int*)d_in[1];
  const float* wt = (const float*)d_in[2];
  float* out = (float*)d_out;

  char* ws = (char*)d_ws;
  unsigned char* wn = (unsigned char*)ws;                      //  51,200,000 B
  unsigned char* xn = (unsigned char*)(ws + 51200000);         //     262,144 B
  float* partial    = (float*)(ws + 51462144);                 //   1,601,536 B
  float* tgt        = (float*)(ws + 53063680);                 //       2,048 B
  float* nll        = (float*)(ws + 53065728);                 //       2,048 B

  rownorm_fp8<<<(CCLS + BATCH) / 4, 256, 0, stream>>>(wt, x, wn, xn);
  cosface_gemm<<<2 * NT, 512, 0, stream>>>(xn, wn, gt, partial, tgt);
  nll_rows<<<BATCH, 64, 0, stream>>>(partial, tgt, nll);
  reduce_mean<<<1, BATCH, 0, stream>>>(nll, out);
}

// Round 11
// 349.352 us; speedup vs baseline: 1.0543x; 1.0543x over previous
//
#include <hip/hip_runtime.h>
#include <hip/hip_bf16.h>

#define DIM 512
#define BATCH 512
#define CCLS 100000
#define BM 256
#define BN 128
#define NT 782   // ceil(100000/128)

typedef __attribute__((ext_vector_type(4))) float f32x4;

__device__ __forceinline__ void async_copy16(const unsigned char* g, unsigned char* l) {
  __builtin_amdgcn_global_load_lds((const __attribute__((address_space(1))) void*)g,
                                   (__attribute__((address_space(3))) void*)l, 16, 0, 0);
}

// One wave per row: read fp32 row, L2-normalize (fp32), write fp8 e4m3 row.
// (R0's kernel, proven at HBM roofline ~41 us.)
__global__ __launch_bounds__(256) void rownorm_fp8(const float* __restrict__ wt,
                                                   const float* __restrict__ x,
                                                   unsigned char* __restrict__ wn,
                                                   unsigned char* __restrict__ xn) {
  int wave = threadIdx.x >> 6;
  int lane = threadIdx.x & 63;
  int row4 = blockIdx.x * 4 + wave;
  const float* in;
  unsigned char* out;
  int row;
  if (row4 < CCLS) { in = wt; out = wn; row = row4; }
  else             { in = x;  out = xn; row = row4 - CCLS; }
  const float4* src = (const float4*)(in + (size_t)row * DIM);
  float4 v0 = src[2 * lane];
  float4 v1 = src[2 * lane + 1];
  float ss = v0.x*v0.x + v0.y*v0.y + v0.z*v0.z + v0.w*v0.w
           + v1.x*v1.x + v1.y*v1.y + v1.z*v1.z + v1.w*v1.w;
  #pragma unroll
  for (int off = 32; off > 0; off >>= 1) ss += __shfl_xor(ss, off, 64);
  float r = 1.0f / fmaxf(sqrtf(ss), 1e-12f);
  int p0 = __builtin_amdgcn_cvt_pk_fp8_f32(v0.x * r, v0.y * r, 0, false);
  p0     = __builtin_amdgcn_cvt_pk_fp8_f32(v0.z * r, v0.w * r, p0, true);
  int p1 = __builtin_amdgcn_cvt_pk_fp8_f32(v1.x * r, v1.y * r, 0, false);
  p1     = __builtin_amdgcn_cvt_pk_fp8_f32(v1.z * r, v1.w * r, p1, true);
  ((int2*)(out + (size_t)row * DIM))[lane] = make_int2(p0, p1);
}

// 256x128 tile fp8 GEMM, K=512, BK=64 (8 iters), 512 threads = 8 waves
// (4m x 2n), 64x64 per-wave tile (acc[4][4] = 64 AGPR, R0's no-spill
// profile at (512,4)).
// R10 post-mortem fixes:
//  1. Bank conflicts: swizzle on (m>>1)&3 -- rows 0..7 hit 8 distinct
//     bank-groups (row parity supplies +-16, slot supplies x4), 2-way = free.
//     R10's (m&3) collapsed 16 lanes onto 4 groups (4-way, 1.58x).
//  2. Counted vmcnt (T4): 3-deep LDS ring (72 KB -> 2 blocks/CU), depth-2
//     prefetch, per iter: vmcnt(3) [stage kk landed, stage kk+1 still
//     flying] -> s_barrier -> STAGE(kk+2) -> compute(kk). The load queue
//     NEVER drains in the main loop. Race-free: STAGE target buf[(kk+2)%3]
//     was last read at compute(kk-1), which precedes this barrier for all
//     waves.
__global__ __launch_bounds__(512, 4) void cosface_gemm(
    const unsigned char* __restrict__ xn,
    const unsigned char* __restrict__ wn,
    const int* __restrict__ gt,
    float* __restrict__ partial,
    float* __restrict__ tgt) {
  __shared__ __align__(16) unsigned char lds_a[3][BM * 64];   // 48 KB
  __shared__ __align__(16) unsigned char lds_b[3][BN * 64];   // 24 KB
  __shared__ float lds_rowsum[BM];
  __shared__ int lds_gt[BM];

  const int tid = threadIdx.x;
  const int lane = tid & 63;
  const int w = tid >> 6;          // wave 0..7
  const int wm = w >> 1;           // 0..3  (64-row slice)
  const int wn_ = w & 1;           // 0..1  (64-col slice)

  // Bijective XCD swizzle (m204 form): 1564 = 4 xcds x 196 + 4 x 195.
  int orig = blockIdx.x;
  int xcd = orig & 7;
  int f = (xcd < 4 ? xcd * 196 : 4 * 196 + (xcd - 4) * 195) + (orig >> 3);
  const int mt = f & 1;            // 0..1
  const int nt = f >> 1;           // 0..781

  if (tid < BM) {
    lds_rowsum[tid] = 0.f;
    lds_gt[tid] = gt[mt * BM + tid];
  }

  // Staging (BK=64): A 1024 chunks of 16B (2/thread), B 512 (1/thread).
  // chunk c -> row m = c>>2, slot qs = c&3, content chunk qg = qs^((m>>1)&3).
  unsigned int oa[2];
  unsigned int ob;
  #pragma unroll
  for (int j = 0; j < 2; ++j) {
    int c = j * 512 + tid;
    int m = c >> 2;
    int qg = (c & 3) ^ ((m >> 1) & 3);
    oa[j] = (unsigned int)(mt * BM + m) * DIM + qg * 16;
  }
  {
    int m = tid >> 2;
    int qg = (tid & 3) ^ ((m >> 1) & 3);
    int rowB = nt * BN + m;
    if (rowB >= CCLS) rowB = CCLS - 1;   // clamp; excluded in epilogue
    ob = (unsigned int)rowB * DIM + qg * 16;
  }

#define STAGE(sel, kk) do {                                                  \
    _Pragma("unroll")                                                        \
    for (int j = 0; j < 2; ++j)                                              \
      async_copy16(xn + oa[j] + (kk) * 64,                                   \
                   &lds_a[sel][(j * 512 + tid) * 16]);                       \
    async_copy16(wn + ob + (kk) * 64, &lds_b[sel][tid * 16]);                \
  } while (0)

  f32x4 acc[4][4];
  #pragma unroll
  for (int i = 0; i < 4; ++i)
    #pragma unroll
    for (int j = 0; j < 4; ++j)
      acc[i][j] = (f32x4){0.f, 0.f, 0.f, 0.f};

  const int quad = lane >> 4;
  const int l15 = lane & 15;
  const int sw = (l15 >> 1) & 3;   // (row>>1)&3: row = base(x16) + l15, so
                                   // constant across the i*16 fragment rows
  const int csbase = quad >> 1;    // k-slice s: cs = s*2 + (quad>>1)
  const int h = (quad & 1) * 8;

  // Prologue: stage tiles 0 and 1 (depth-2 fill).
  STAGE(0, 0);
  STAGE(1, 1);

  #pragma unroll
  for (int kk = 0; kk < 8; ++kk) {
    // Wait for stage(kk) only -- stage(kk+1) stays in flight.
    if (kk < 7) asm volatile("s_waitcnt vmcnt(3)" ::: "memory");
    else        asm volatile("s_waitcnt vmcnt(0)" ::: "memory");
    __builtin_amdgcn_s_barrier();
    asm volatile("" ::: "memory");
    // Stage kk+2 into the ring slot last read at compute(kk-1) -- all
    // waves passed that read before the barrier above.
    if (kk < 6) STAGE((kk + 2) % 3, kk + 2);

    const int cur = kk % 3;
    #pragma unroll
    for (int s = 0; s < 2; ++s) {
      int cs = s * 2 + csbase;
      long long af[4], bf[4];
      #pragma unroll
      for (int i = 0; i < 4; ++i)
        af[i] = *(const long long*)&lds_a[cur][(wm * 64 + i * 16 + l15) * 64 + ((cs ^ sw) * 16) + h];
      #pragma unroll
      for (int j = 0; j < 4; ++j)
        bf[j] = *(const long long*)&lds_b[cur][(wn_ * 64 + j * 16 + l15) * 64 + ((cs ^ sw) * 16) + h];
      #pragma unroll
      for (int i = 0; i < 4; ++i)
        #pragma unroll
        for (int j = 0; j < 4; ++j)
          acc[i][j] = __builtin_amdgcn_mfma_f32_16x16x32_fp8_fp8(af[i], bf[j], acc[i][j], 0, 0, 0);
    }
  }
#undef STAGE

  // Epilogue (R0's, verified): logit = 64*cos (-22.4 at gt);
  // rowsum += sum_n exp(logit-64).
  #pragma unroll
  for (int i = 0; i < 4; ++i) {
    #pragma unroll
    for (int reg = 0; reg < 4; ++reg) {
      int m_loc = wm * 64 + i * 16 + quad * 4 + reg;
      int m_g = mt * BM + m_loc;
      int gtm = lds_gt[m_loc];
      float s = 0.f;
      #pragma unroll
      for (int j = 0; j < 4; ++j) {
        int n_g = nt * BN + wn_ * 64 + j * 16 + l15;
        float logit = 64.f * acc[i][j][reg];
        if (n_g == gtm) {
          logit -= 64.f * 0.35f;
          tgt[m_g] = logit;
        }
        if (n_g < CCLS) s += __expf(logit - 64.f);
      }
      #pragma unroll
      for (int off = 1; off < 16; off <<= 1) s += __shfl_xor(s, off, 64);
      if (l15 == 0) atomicAdd(&lds_rowsum[m_loc], s);
    }
  }
  __syncthreads();
  if (tid < BM)
    partial[(size_t)(mt * BM + tid) * NT + nt] = lds_rowsum[tid];
}

// One wave per row m: sum partial[m][0..NT) (contiguous), emit nll[m].
__global__ __launch_bounds__(64) void nll_rows(const float* __restrict__ partial,
                                               const float* __restrict__ tgt,
                                               float* __restrict__ nll) {
  int m = blockIdx.x;
  int lane = threadIdx.x;
  const float* row = partial + (size_t)m * NT;
  float s = 0.f;
  for (int t = lane; t < NT; t += 64) s += row[t];
  #pragma unroll
  for (int off = 32; off > 0; off >>= 1) s += __shfl_xor(s, off, 64);
  if (lane == 0) nll[m] = (logf(s) + 64.f) - tgt[m];
}

__global__ __launch_bounds__(512) void reduce_mean(const float* __restrict__ nll,
                                                   float* __restrict__ out) {
  __shared__ float red[BATCH];
  int m = threadIdx.x;
  red[m] = nll[m];
  __syncthreads();
  for (int k = 256; k > 0; k >>= 1) {
    if (m < k) red[m] += red[m + k];
    __syncthreads();
  }
  if (m == 0) out[0] = red[0] * (1.0f / BATCH);
}

extern "C" void kernel_launch(void* const* d_in, const int* in_sizes, int n_in,
                              void* d_out, int out_size, void* d_ws, size_t ws_size,
                              hipStream_t stream) {
  const float* x  = (const float*)d_in[0];
  const int*   gt = (const int*)d_in[1];
  const float* wt = (const float*)d_in[2];
  float* out = (float*)d_out;

  char* ws = (char*)d_ws;
  unsigned char* wn = (unsigned char*)ws;                      //  51,200,000 B
  unsigned char* xn = (unsigned char*)(ws + 51200000);         //     262,144 B
  float* partial    = (float*)(ws + 51462144);                 //   1,601,536 B
  float* tgt        = (float*)(ws + 53063680);                 //       2,048 B
  float* nll        = (float*)(ws + 53065728);                 //       2,048 B

  rownorm_fp8<<<(CCLS + BATCH) / 4, 256, 0, stream>>>(wt, x, wn, xn);
  cosface_gemm<<<2 * NT, 512, 0, stream>>>(xn, wn, gt, partial, tgt);
  nll_rows<<<BATCH, 64, 0, stream>>>(partial, tgt, nll);
  reduce_mean<<<1, BATCH, 0, stream>>>(nll, out);
}